// Round 4
// baseline (259.584 us; speedup 1.0000x reference)
//
#include <hip/hip_runtime.h>

#define N_TR 1024
#define H_DIM 128
#define P_PAIRS 523776   // N*(N-1)/2
#define TI 8             // i-rows per k_pairs block
// ws float offsets
#define WS_U    0
#define WS_V    131072
#define WS_UA   262144
#define WS_VA   393216
#define WS_SUMU 524288   // per i: {sumU, sumU2} (cons net)
#define WS_SUMV 526336   // per j: {sumV, sumV2} (cons net, V includes bias)
// ws byte offsets
#define WS_FRAG_BYTES 2113536u  // 12288 bf16 = 24576 B
#define WS_D_BYTES    2138112u  // 1024*1024 bf16 = 2 MB  (total ws use ~4.04 MB)

typedef __attribute__((ext_vector_type(8))) short bf16x8;
typedef __attribute__((ext_vector_type(4))) float f32x4;

__device__ __forceinline__ float bf2f(unsigned short u) {
  return __uint_as_float(((unsigned)u) << 16);
}
__device__ __forceinline__ short f2bfs(float f) {
  unsigned x = __float_as_uint(f);
  unsigned r = x + 0x7fffu + ((x >> 16) & 1u);
  return (short)(r >> 16);
}
// pack two f32 -> two bf16 in one word: hi=f1, lo=f0 (round-half-up; validated R2/R3)
__device__ __forceinline__ unsigned pk_bf16(float f0, float f1) {
  unsigned a0 = __float_as_uint(f0) + 0x8000u;
  unsigned a1 = __float_as_uint(f1) + 0x8000u;
  return __builtin_amdgcn_perm(a1, a0, 0x07060302u);
}
// branch-free tanh-form GELU (validated R3: absmax 0.0039 total)
__device__ __forceinline__ float geluf(float x) {
  float u = x * x;
  float p = __builtin_fmaf(u, 0.10294324f, 2.30220820f);
  float e = __builtin_amdgcn_exp2f(x * p);
  float r = __builtin_amdgcn_rcpf(e + 1.0f);
  return __builtin_fmaf(-x, r, x);
}
__device__ __forceinline__ float sigmoidf_(float x) {
  float e = __builtin_amdgcn_exp2f(x * -1.4426950408889634f);
  return __builtin_amdgcn_rcpf(1.0f + e);
}

// ================= K_PRE: fused {uv+sums | repack | imp} ===================
// grid 816: [0,512) uv (2 rows/block), [512,560) repack, [560,816) imp (4 rows)
__global__ __launch_bounds__(256) void k_pre(
    const float* __restrict__ emb, const float* __restrict__ tf,
    const float* __restrict__ cW1, const float* __restrict__ cb1,
    const float* __restrict__ aW1, const float* __restrict__ ab1,
    const float* __restrict__ cW2, const float* __restrict__ aW2,
    const float* __restrict__ iW1, const float* __restrict__ ib1,
    const float* __restrict__ iW2, const float* __restrict__ ib2,
    float* __restrict__ ws, unsigned short* __restrict__ frag,
    float* __restrict__ out)
{
  __shared__ __align__(16) float sE[2][128];
  __shared__ float sRed[2][8];
  const int blk = blockIdx.x;
  const int t = threadIdx.x;
  const int lane = t & 63, wave = t >> 6;

  if (blk < 512) {
    // ---------------- uv body: U/V/Ua/Va + cons row sums ----------------
    const int b = blk;
    { int r = t >> 7, c = t & 127; sE[r][c] = emb[(b * 2 + r) * 128 + c]; }
    __syncthreads();
    const int k = t & 127;
    const bool cons = (t < 128);
    const float* W    = cons ? cW1 : aW1;
    const float* bias = cons ? cb1 : ab1;
    float* outU = ws + (cons ? WS_U : WS_UA);
    float* outV = ws + (cons ? WS_V : WS_VA);
    float accU0 = 0.f, accU1 = 0.f, accV0 = 0.f, accV1 = 0.f;
    for (int c = 0; c < 128; ++c) {
      float wt = W[c * 128 + k];
      float wb = W[(128 + c) * 128 + k];
      float e0 = sE[0][c], e1 = sE[1][c];
      accU0 = __builtin_fmaf(e0, wt, accU0);
      accU1 = __builtin_fmaf(e1, wt, accU1);
      accV0 = __builtin_fmaf(e0, wb, accV0);
      accV1 = __builtin_fmaf(e1, wb, accV1);
    }
    const float bv = bias[k];
    const float vb0 = accV0 + bv, vb1 = accV1 + bv;
    outU[(b * 2 + 0) * 128 + k] = accU0;
    outU[(b * 2 + 1) * 128 + k] = accU1;
    outV[(b * 2 + 0) * 128 + k] = vb0;
    outV[(b * 2 + 1) * 128 + k] = vb1;
    // cons-net row sums: su, qu (U), sv, qv (V incl. bias)
    if (t < 128) {
      float vals[8] = {accU0, accU0 * accU0, accU1, accU1 * accU1,
                       vb0, vb0 * vb0, vb1, vb1 * vb1};
      #pragma unroll
      for (int msk = 1; msk <= 32; msk <<= 1)
        #pragma unroll
        for (int v = 0; v < 8; ++v) vals[v] += __shfl_xor(vals[v], msk, 64);
      if ((t & 63) == 0)
        #pragma unroll
        for (int v = 0; v < 8; ++v) sRed[t >> 6][v] = vals[v];
    }
    __syncthreads();
    if (t == 0) {
      const int i0 = b * 2;
      ws[WS_SUMU + i0 * 2 + 0]       = sRed[0][0] + sRed[1][0];
      ws[WS_SUMU + i0 * 2 + 1]       = sRed[0][1] + sRed[1][1];
      ws[WS_SUMU + (i0 + 1) * 2 + 0] = sRed[0][2] + sRed[1][2];
      ws[WS_SUMU + (i0 + 1) * 2 + 1] = sRed[0][3] + sRed[1][3];
      ws[WS_SUMV + i0 * 2 + 0]       = sRed[0][4] + sRed[1][4];
      ws[WS_SUMV + i0 * 2 + 1]       = sRed[0][5] + sRed[1][5];
      ws[WS_SUMV + (i0 + 1) * 2 + 0] = sRed[0][6] + sRed[1][6];
      ws[WS_SUMV + (i0 + 1) * 2 + 1] = sRed[0][7] + sRed[1][7];
    }
  } else if (blk < 560) {
    // ---------------- repack body: W2 -> MFMA B-frag order (f32->bf16) ----
    int u = (blk - 512) * 256 + t;   // 0..12287
    if (u < 8192) {
      int j = u & 7, ln = (u >> 3) & 63, ks = (u >> 9) & 3, nt = u >> 11;
      frag[u] = (unsigned short)f2bfs(cW2[(ks * 32 + (ln >> 4) * 8 + j) * 64 + nt * 16 + (ln & 15)]);
    } else {
      int v = u - 8192;
      int j = v & 7, ln = (v >> 3) & 63, ks = (v >> 9) & 3, nt = v >> 11;
      frag[u] = (unsigned short)f2bfs(aW2[(ks * 32 + (ln >> 4) * 8 + j) * 32 + nt * 16 + (ln & 15)]);
    }
  } else {
    // ---------------- imp body: 1 row per wave ----------------------------
    const int r = (blk - 560) * 4 + wave;
    float acc = 0.f;
    for (int c = 0; c < 128; ++c)
      acc = __builtin_fmaf(emb[r * 128 + c], iW1[c * 64 + lane], acc);
    #pragma unroll
    for (int c = 0; c < 5; ++c)
      acc = __builtin_fmaf(tf[r * 5 + c], iW1[(128 + c) * 64 + lane], acc);
    float d = geluf(acc + ib1[lane]) * iW2[lane];
    #pragma unroll
    for (int msk = 32; msk; msk >>= 1) d += __shfl_xor(d, msk, 64);
    if (lane == 0) out[2 * P_PAIRS + r] = sigmoidf_(d + ib2[0]);
  }
}

// ================= K_DOT: D = U · V^T (bf16 out), 64x64 tiles =============
__global__ __launch_bounds__(256) void k_dot(
    const float* __restrict__ ws, unsigned short* __restrict__ D)
{
  const int bx = blockIdx.x, by = blockIdx.y;   // 16 x 16
  const int t = threadIdx.x, lane = t & 63, w = t >> 6;
  const int m = lane & 15, g = lane >> 4;
  const float* Ur = ws + WS_U + (by * 64 + w * 16 + m) * 128;
  bf16x8 aF[4];
  #pragma unroll
  for (int ks = 0; ks < 4; ++ks) {
    const int off = ks * 32 + g * 8;
    float4 a0 = *(const float4*)(Ur + off);
    float4 a1 = *(const float4*)(Ur + off + 4);
    int4 p; p.x = pk_bf16(a0.x, a0.y); p.y = pk_bf16(a0.z, a0.w);
    p.z = pk_bf16(a1.x, a1.y); p.w = pk_bf16(a1.z, a1.w);
    aF[ks] = __builtin_bit_cast(bf16x8, p);
  }
  const f32x4 zero = {0.f, 0.f, 0.f, 0.f};
  f32x4 acc[4] = {zero, zero, zero, zero};
  #pragma unroll
  for (int nt = 0; nt < 4; ++nt) {
    const float* Vr = ws + WS_V + (bx * 64 + nt * 16 + m) * 128;
    #pragma unroll
    for (int ks = 0; ks < 4; ++ks) {
      const int off = ks * 32 + g * 8;
      float4 b0 = *(const float4*)(Vr + off);
      float4 b1 = *(const float4*)(Vr + off + 4);
      int4 p; p.x = pk_bf16(b0.x, b0.y); p.y = pk_bf16(b0.z, b0.w);
      p.z = pk_bf16(b1.x, b1.y); p.w = pk_bf16(b1.z, b1.w);
      acc[nt] = __builtin_amdgcn_mfma_f32_16x16x32_bf16(
          aF[ks], __builtin_bit_cast(bf16x8, p), acc[nt], 0, 0, 0);
    }
  }
  #pragma unroll
  for (int nt = 0; nt < 4; ++nt)
    #pragma unroll
    for (int r = 0; r < 4; ++r)
      D[(by * 64 + w * 16 + g * 4 + r) * 1024 + bx * 64 + nt * 16 + m] =
          (unsigned short)f2bfs(acc[nt][r]);
}

// ================= K_PAIRS ================================================
// grid (16 jt, 128 ib); 4 waves; wave w owns j = jt*64+w*16+(0..15); TI=8 i's.
// LN stats precomputed: mean=(su+sv)/128, E[x^2]=(qu+qv+2*dot)/128.
__global__ __launch_bounds__(256, 5) void k_pairs(
    const float* __restrict__ ws, const unsigned short* __restrict__ frag,
    const unsigned short* __restrict__ D,
    const float* __restrict__ lng, const float* __restrict__ lnb,
    const float* __restrict__ cb2, const float* __restrict__ cW3,
    const float* __restrict__ cb3,
    const float* __restrict__ ab2, const float* __restrict__ aW3,
    const float* __restrict__ ab3,
    float* __restrict__ out)
{
  const int jt = blockIdx.x;
  const int i0 = blockIdx.y * TI;
  if (jt * 64 + 63 <= i0) return;

  __shared__ __align__(16) unsigned short sFrag[12288];
  __shared__ __align__(16) float sG[128];
  __shared__ __align__(16) float sB[128];
  __shared__ float sSt[TI * 2];
  const int t = threadIdx.x;
  {
    const uint4* src = (const uint4*)frag;
    uint4* dst = (uint4*)sFrag;
    #pragma unroll
    for (int q = 0; q < 6; ++q) dst[t + q * 256] = src[t + q * 256];
  }
  if (t < 128) { sG[t] = lng[t]; sB[t] = lnb[t]; }
  if (t < TI * 2) sSt[t] = ws[WS_SUMU + i0 * 2 + t];
  __syncthreads();

  const int lane = t & 63;
  const int wave = t >> 6;
  const int m = lane & 15;
  const int g = lane >> 4;
  const int j = jt * 64 + wave * 16 + m;
  const float* Vrow  = ws + WS_V  + j * 128;
  const float* Varow = ws + WS_VA + j * 128;
  const float svj = ws[WS_SUMV + j * 2];
  const float qvj = ws[WS_SUMV + j * 2 + 1];

  float cb2v[4], cw3v[4], ab2v[2], aw3v[2];
  #pragma unroll
  for (int nt = 0; nt < 4; ++nt) { cb2v[nt] = cb2[nt * 16 + m]; cw3v[nt] = cW3[nt * 16 + m]; }
  #pragma unroll
  for (int nt = 0; nt < 2; ++nt) { ab2v[nt] = ab2[nt * 16 + m]; aw3v[nt] = aW3[nt * 16 + m]; }
  const float cb3s = cb3[0], ab3s = ab3[0];
  const bf16x8* bfr = (const bf16x8*)sFrag;
  const f32x4 zero = {0.f, 0.f, 0.f, 0.f};
  const float inv128 = 0.0078125f;

  for (int it = 0; it < TI; ++it) {
    const int i = i0 + it;
    if (jt * 64 + wave * 16 + 15 <= i) continue;   // wave-uniform skip

    // ---- precomputed LN stats ----
    const float su = sSt[it * 2], qu = sSt[it * 2 + 1];
    const float dot = bf2f(D[i * 1024 + j]);
    const float mean = (su + svj) * inv128;
    const float ex2  = __builtin_fmaf(2.f, dot, qu + qvj) * inv128;
    const float var  = ex2 - mean * mean;
    const float rstd = rsqrtf(var + 1e-5f);

    const float* Urow  = ws + WS_U  + i * 128;
    const float* Uarow = ws + WS_UA + i * 128;

    // ---- cons phase 1: y = gelu(((U+V)-mean)*rstd*G + B), pack bf16 ----
    int4 pC[4];
    #pragma unroll
    for (int ks = 0; ks < 4; ++ks) {
      const int off = ks * 32 + g * 8;
      float4 u0 = *(const float4*)(Urow + off);
      float4 u1 = *(const float4*)(Urow + off + 4);
      float4 v0 = *(const float4*)(Vrow + off);
      float4 v1 = *(const float4*)(Vrow + off + 4);
      float4 g0 = *(const float4*)(sG + off);
      float4 g1 = *(const float4*)(sG + off + 4);
      float4 b0 = *(const float4*)(sB + off);
      float4 b1 = *(const float4*)(sB + off + 4);
      float us[8] = {u0.x,u0.y,u0.z,u0.w,u1.x,u1.y,u1.z,u1.w};
      float vs[8] = {v0.x,v0.y,v0.z,v0.w,v1.x,v1.y,v1.z,v1.w};
      float gg[8] = {g0.x,g0.y,g0.z,g0.w,g1.x,g1.y,g1.z,g1.w};
      float bb[8] = {b0.x,b0.y,b0.z,b0.w,b1.x,b1.y,b1.z,b1.w};
      float y[8];
      #pragma unroll
      for (int s = 0; s < 8; ++s) {
        float x = us[s] + vs[s];
        float tq = (x - mean) * rstd;
        y[s] = geluf(__builtin_fmaf(tq, gg[s], bb[s]));
      }
      pC[ks].x = pk_bf16(y[0], y[1]); pC[ks].y = pk_bf16(y[2], y[3]);
      pC[ks].z = pk_bf16(y[4], y[5]); pC[ks].w = pk_bf16(y[6], y[7]);
    }

    // ---- assoc phase 1: relu(Ua+Va), pack bf16 ----
    int4 pA[4];
    #pragma unroll
    for (int ks = 0; ks < 4; ++ks) {
      const int off = ks * 32 + g * 8;
      float4 u0 = *(const float4*)(Uarow + off);
      float4 u1 = *(const float4*)(Uarow + off + 4);
      float4 v0 = *(const float4*)(Varow + off);
      float4 v1 = *(const float4*)(Varow + off + 4);
      float us[8] = {u0.x,u0.y,u0.z,u0.w,u1.x,u1.y,u1.z,u1.w};
      float vs[8] = {v0.x,v0.y,v0.z,v0.w,v1.x,v1.y,v1.z,v1.w};
      float r[8];
      #pragma unroll
      for (int s = 0; s < 8; ++s) r[s] = fmaxf(us[s] + vs[s], 0.f);
      pA[ks].x = pk_bf16(r[0], r[1]); pA[ks].y = pk_bf16(r[2], r[3]);
      pA[ks].z = pk_bf16(r[4], r[5]); pA[ks].w = pk_bf16(r[6], r[7]);
    }

    // ---- layer-2 GEMMs via MFMA ----
    f32x4 accC[4] = {zero, zero, zero, zero};
    f32x4 accA[2] = {zero, zero};
    #pragma unroll
    for (int ks = 0; ks < 4; ++ks) {
      bf16x8 aC = __builtin_bit_cast(bf16x8, pC[ks]);
      bf16x8 aA = __builtin_bit_cast(bf16x8, pA[ks]);
      #pragma unroll
      for (int nt = 0; nt < 4; ++nt)
        accC[nt] = __builtin_amdgcn_mfma_f32_16x16x32_bf16(
            aC, bfr[(nt * 4 + ks) * 64 + lane], accC[nt], 0, 0, 0);
      #pragma unroll
      for (int nt = 0; nt < 2; ++nt)
        accA[nt] = __builtin_amdgcn_mfma_f32_16x16x32_bf16(
            aA, bfr[1024 + (nt * 4 + ks) * 64 + lane], accA[nt], 0, 0, 0);
    }

    // ---- layer 3: bias + act + dot W3, reduce over n (lane&15) ----
    float sc[4] = {0.f, 0.f, 0.f, 0.f};
    float sa[4] = {0.f, 0.f, 0.f, 0.f};
    #pragma unroll
    for (int nt = 0; nt < 4; ++nt)
      #pragma unroll
      for (int r = 0; r < 4; ++r)
        sc[r] = __builtin_fmaf(geluf(accC[nt][r] + cb2v[nt]), cw3v[nt], sc[r]);
    #pragma unroll
    for (int nt = 0; nt < 2; ++nt)
      #pragma unroll
      for (int r = 0; r < 4; ++r)
        sa[r] = __builtin_fmaf(fmaxf(accA[nt][r] + ab2v[nt], 0.f), aw3v[nt], sa[r]);
    #pragma unroll
    for (int msk = 1; msk <= 8; msk <<= 1) {
      #pragma unroll
      for (int r = 0; r < 4; ++r) {
        sc[r] += __shfl_xor(sc[r], msk, 64);
        sa[r] += __shfl_xor(sa[r], msk, 64);
      }
    }
    if (m < 4) {
      const int jr = jt * 64 + wave * 16 + g * 4 + m;
      if (jr > i) {
        const int p = i * (2 * N_TR - i - 1) / 2 + (jr - i - 1);
        out[p]           = sigmoidf_(sc[m] + cb3s);
        out[P_PAIRS + p] = sigmoidf_(sa[m] + ab3s);
      }
    }
  }
}

extern "C" void kernel_launch(void* const* d_in, const int* in_sizes, int n_in,
                              void* d_out, int out_size, void* d_ws, size_t ws_size,
                              hipStream_t stream) {
  const float* emb = (const float*)d_in[0];
  const float* tf  = (const float*)d_in[1];
  const float* cW1 = (const float*)d_in[2];
  const float* cb1 = (const float*)d_in[3];
  const float* lng = (const float*)d_in[4];
  const float* lnb = (const float*)d_in[5];
  const float* cW2 = (const float*)d_in[6];
  const float* cb2 = (const float*)d_in[7];
  const float* cW3 = (const float*)d_in[8];
  const float* cb3 = (const float*)d_in[9];
  const float* aW1 = (const float*)d_in[10];
  const float* ab1 = (const float*)d_in[11];
  const float* aW2 = (const float*)d_in[12];
  const float* ab2 = (const float*)d_in[13];
  const float* aW3 = (const float*)d_in[14];
  const float* ab3 = (const float*)d_in[15];
  const float* iW1 = (const float*)d_in[16];
  const float* ib1 = (const float*)d_in[17];
  const float* iW2 = (const float*)d_in[18];
  const float* ib2 = (const float*)d_in[19];

  float* ws = (float*)d_ws;
  unsigned short* frag = (unsigned short*)((char*)d_ws + WS_FRAG_BYTES);
  unsigned short* D    = (unsigned short*)((char*)d_ws + WS_D_BYTES);
  float* out = (float*)d_out;

  hipLaunchKernelGGL(k_pre, dim3(816), dim3(256), 0, stream,
                     emb, tf, cW1, cb1, aW1, ab1, cW2, aW2,
                     iW1, ib1, iW2, ib2, ws, frag, out);
  hipLaunchKernelGGL(k_dot, dim3(16, 16), dim3(256), 0, stream, ws, D);
  hipLaunchKernelGGL(k_pairs, dim3(16, 128), dim3(256), 0, stream,
                     ws, frag, D, lng, lnb, cb2, cW3, cb3, ab2, aW3, ab3, out);
}

// Round 5
// 173.183 us; speedup vs baseline: 1.4989x; 1.4989x over previous
//
#include <hip/hip_runtime.h>

#define N_TR 1024
#define H_DIM 128
#define P_PAIRS 523776   // N*(N-1)/2
#define TI 8             // i-rows per k_pairs tile
// ws float offsets
#define WS_U    0
#define WS_V    131072
#define WS_UA   262144
#define WS_VA   393216
#define WS_SUMU 524288   // per i: {sumU, sumU2} (cons net)
#define WS_SUMV 526336   // per j: {sumV, sumV2} (cons net, V includes bias)
// ws byte offsets
#define WS_FRAG_BYTES 2113536u  // 12288 bf16 = 24576 B

typedef __attribute__((ext_vector_type(8))) short bf16x8;
typedef __attribute__((ext_vector_type(4))) float f32x4;

__device__ __forceinline__ short f2bfs(float f) {
  unsigned x = __float_as_uint(f);
  unsigned r = x + 0x7fffu + ((x >> 16) & 1u);
  return (short)(r >> 16);
}
// pack two f32 -> two bf16 in one word: hi=f1, lo=f0 (validated R2-R4)
__device__ __forceinline__ unsigned pk_bf16(float f0, float f1) {
  unsigned a0 = __float_as_uint(f0) + 0x8000u;
  unsigned a1 = __float_as_uint(f1) + 0x8000u;
  return __builtin_amdgcn_perm(a1, a0, 0x07060302u);
}
// branch-free tanh-form GELU (validated: absmax 0.0039 total)
__device__ __forceinline__ float geluf(float x) {
  float u = x * x;
  float p = __builtin_fmaf(u, 0.10294324f, 2.30220820f);
  float e = __builtin_amdgcn_exp2f(x * p);
  float r = __builtin_amdgcn_rcpf(e + 1.0f);
  return __builtin_fmaf(-x, r, x);
}
__device__ __forceinline__ float sigmoidf_(float x) {
  float e = __builtin_amdgcn_exp2f(x * -1.4426950408889634f);
  return __builtin_amdgcn_rcpf(1.0f + e);
}
// 16-lane (DPP-row) sum reduction on the VALU pipe (no LDS traffic).
// Stages: xor1 (quad_perm 1,0,3,2), xor2 (quad_perm 2,3,0,1),
// half-mirror (combines 4-groups), mirror (combines 8-groups).
template <int CTRL>
__device__ __forceinline__ float dpp_add(float x) {
  int v = __builtin_amdgcn_update_dpp(0, __float_as_int(x), CTRL, 0xf, 0xf, true);
  return x + __int_as_float(v);
}
__device__ __forceinline__ float red16(float x) {
  x = dpp_add<0xB1>(x);
  x = dpp_add<0x4E>(x);
  x = dpp_add<0x141>(x);
  x = dpp_add<0x140>(x);
  return x;
}

// ================= K_PRE: fused {uv+sums | repack | imp} ===================
// grid 816: [0,512) uv (2 rows/block), [512,560) repack, [560,816) imp
__global__ __launch_bounds__(256) void k_pre(
    const float* __restrict__ emb, const float* __restrict__ tf,
    const float* __restrict__ cW1, const float* __restrict__ cb1,
    const float* __restrict__ aW1, const float* __restrict__ ab1,
    const float* __restrict__ cW2, const float* __restrict__ aW2,
    const float* __restrict__ iW1, const float* __restrict__ ib1,
    const float* __restrict__ iW2, const float* __restrict__ ib2,
    float* __restrict__ ws, unsigned short* __restrict__ frag,
    float* __restrict__ out)
{
  __shared__ __align__(16) float sE[2][128];
  __shared__ float sRed[2][8];
  const int blk = blockIdx.x;
  const int t = threadIdx.x;
  const int lane = t & 63, wave = t >> 6;

  if (blk < 512) {
    const int b = blk;
    { int r = t >> 7, c = t & 127; sE[r][c] = emb[(b * 2 + r) * 128 + c]; }
    __syncthreads();
    const int k = t & 127;
    const bool cons = (t < 128);
    const float* W    = cons ? cW1 : aW1;
    const float* bias = cons ? cb1 : ab1;
    float* outU = ws + (cons ? WS_U : WS_UA);
    float* outV = ws + (cons ? WS_V : WS_VA);
    float accU0 = 0.f, accU1 = 0.f, accV0 = 0.f, accV1 = 0.f;
    for (int c = 0; c < 128; ++c) {
      float wt = W[c * 128 + k];
      float wb = W[(128 + c) * 128 + k];
      float e0 = sE[0][c], e1 = sE[1][c];
      accU0 = __builtin_fmaf(e0, wt, accU0);
      accU1 = __builtin_fmaf(e1, wt, accU1);
      accV0 = __builtin_fmaf(e0, wb, accV0);
      accV1 = __builtin_fmaf(e1, wb, accV1);
    }
    const float bv = bias[k];
    const float vb0 = accV0 + bv, vb1 = accV1 + bv;
    outU[(b * 2 + 0) * 128 + k] = accU0;
    outU[(b * 2 + 1) * 128 + k] = accU1;
    outV[(b * 2 + 0) * 128 + k] = vb0;
    outV[(b * 2 + 1) * 128 + k] = vb1;
    if (t < 128) {
      float vals[8] = {accU0, accU0 * accU0, accU1, accU1 * accU1,
                       vb0, vb0 * vb0, vb1, vb1 * vb1};
      #pragma unroll
      for (int msk = 1; msk <= 32; msk <<= 1)
        #pragma unroll
        for (int v = 0; v < 8; ++v) vals[v] += __shfl_xor(vals[v], msk, 64);
      if ((t & 63) == 0)
        #pragma unroll
        for (int v = 0; v < 8; ++v) sRed[t >> 6][v] = vals[v];
    }
    __syncthreads();
    if (t == 0) {
      const int i0 = b * 2;
      ws[WS_SUMU + i0 * 2 + 0]       = sRed[0][0] + sRed[1][0];
      ws[WS_SUMU + i0 * 2 + 1]       = sRed[0][1] + sRed[1][1];
      ws[WS_SUMU + (i0 + 1) * 2 + 0] = sRed[0][2] + sRed[1][2];
      ws[WS_SUMU + (i0 + 1) * 2 + 1] = sRed[0][3] + sRed[1][3];
      ws[WS_SUMV + i0 * 2 + 0]       = sRed[0][4] + sRed[1][4];
      ws[WS_SUMV + i0 * 2 + 1]       = sRed[0][5] + sRed[1][5];
      ws[WS_SUMV + (i0 + 1) * 2 + 0] = sRed[0][6] + sRed[1][6];
      ws[WS_SUMV + (i0 + 1) * 2 + 1] = sRed[0][7] + sRed[1][7];
    }
  } else if (blk < 560) {
    int u = (blk - 512) * 256 + t;   // 0..12287
    if (u < 8192) {
      int j = u & 7, ln = (u >> 3) & 63, ks = (u >> 9) & 3, nt = u >> 11;
      frag[u] = (unsigned short)f2bfs(cW2[(ks * 32 + (ln >> 4) * 8 + j) * 64 + nt * 16 + (ln & 15)]);
    } else {
      int v = u - 8192;
      int j = v & 7, ln = (v >> 3) & 63, ks = (v >> 9) & 3, nt = v >> 11;
      frag[u] = (unsigned short)f2bfs(aW2[(ks * 32 + (ln >> 4) * 8 + j) * 32 + nt * 16 + (ln & 15)]);
    }
  } else {
    const int r = (blk - 560) * 4 + wave;
    float acc = 0.f;
    for (int c = 0; c < 128; ++c)
      acc = __builtin_fmaf(emb[r * 128 + c], iW1[c * 64 + lane], acc);
    #pragma unroll
    for (int c = 0; c < 5; ++c)
      acc = __builtin_fmaf(tf[r * 5 + c], iW1[(128 + c) * 64 + lane], acc);
    float d = geluf(acc + ib1[lane]) * iW2[lane];
    #pragma unroll
    for (int msk = 32; msk; msk >>= 1) d += __shfl_xor(d, msk, 64);
    if (lane == 0) out[2 * P_PAIRS + r] = sigmoidf_(d + ib2[0]);
  }
}

// ================= K_PAIRS ================================================
// Compact balanced grid: 1088 blocks enumerate only valid (jt, ib) tiles of
// the upper triangle; jt = floor((sqrt(b+1)-1)/2), cum(jt) = 4jt^2+4jt.
// 4 waves; wave w owns j = jt*64+w*16+(0..15); TI=8 i's starting at i0.
// LN stats: mean=(su+sv)/128, E[x^2]=(qu+qv+2*dot)/128; dot computed in-wave
// via 4 MFMAs (U from LDS, V from regs) + LDS transpose (sD).
__global__ __launch_bounds__(256, 4) void k_pairs(
    const float* __restrict__ ws, const unsigned short* __restrict__ frag,
    const float* __restrict__ lng, const float* __restrict__ lnb,
    const float* __restrict__ cb2, const float* __restrict__ cW3,
    const float* __restrict__ cb3,
    const float* __restrict__ ab2, const float* __restrict__ aW3,
    const float* __restrict__ ab3,
    float* __restrict__ out)
{
  const int b = blockIdx.x;
  int jt = (int)((sqrtf((float)b + 1.0f) - 1.0f) * 0.5f);
  while (4 * (jt + 1) * (jt + 1) + 4 * (jt + 1) <= b) ++jt;
  while (jt > 0 && 4 * jt * jt + 4 * jt > b) --jt;
  const int i0 = (b - (4 * jt * jt + 4 * jt)) * 8;

  __shared__ __align__(16) unsigned short sFrag[12288];
  __shared__ __align__(16) float sU[TI][128];
  __shared__ __align__(16) float sUa[TI][128];
  __shared__ __align__(16) float sG[128];
  __shared__ __align__(16) float sB[128];
  __shared__ __align__(16) float sD[4][16][TI];
  __shared__ float sSt[TI * 2];
  const int t = threadIdx.x;
  {
    const uint4* src = (const uint4*)frag;
    uint4* dst = (uint4*)sFrag;
    #pragma unroll
    for (int q = 0; q < 6; ++q) dst[t + q * 256] = src[t + q * 256];
  }
  {
    int r = t >> 5, c4 = (t & 31) * 4;
    *(float4*)&sU[r][c4]  = *(const float4*)(ws + WS_U  + (i0 + r) * 128 + c4);
    *(float4*)&sUa[r][c4] = *(const float4*)(ws + WS_UA + (i0 + r) * 128 + c4);
  }
  if (t < 128) { sG[t] = lng[t]; sB[t] = lnb[t]; }
  if (t < TI * 2) sSt[t] = ws[WS_SUMU + i0 * 2 + t];
  __syncthreads();

  const int lane = t & 63;
  const int wave = t >> 6;
  const int m = lane & 15;
  const int g = lane >> 4;
  const int j = jt * 64 + wave * 16 + m;
  const float* Vrow  = ws + WS_V  + j * 128;
  const float* Varow = ws + WS_VA + j * 128;
  const float svj = ws[WS_SUMV + j * 2];
  const float qvj = ws[WS_SUMV + j * 2 + 1];

  // V row (cons, incl. bias) cached in registers for the whole i-loop
  float vC[4][8];
  bf16x8 aV[4];
  #pragma unroll
  for (int ks = 0; ks < 4; ++ks) {
    const int off = ks * 32 + g * 8;
    float4 a0 = *(const float4*)(Vrow + off);
    float4 a1 = *(const float4*)(Vrow + off + 4);
    vC[ks][0]=a0.x; vC[ks][1]=a0.y; vC[ks][2]=a0.z; vC[ks][3]=a0.w;
    vC[ks][4]=a1.x; vC[ks][5]=a1.y; vC[ks][6]=a1.z; vC[ks][7]=a1.w;
    int4 p; p.x = pk_bf16(a0.x, a0.y); p.y = pk_bf16(a0.z, a0.w);
    p.z = pk_bf16(a1.x, a1.y); p.w = pk_bf16(a1.z, a1.w);
    aV[ks] = __builtin_bit_cast(bf16x8, p);
  }

  // ---- in-wave dot tile: D[j-local, i-local] = U(i).V(j) via 4 MFMAs ----
  const f32x4 zero = {0.f, 0.f, 0.f, 0.f};
  {
    f32x4 accD = zero;
    #pragma unroll
    for (int ks = 0; ks < 4; ++ks) {
      const int off = ks * 32 + g * 8;
      const float* ur = sU[m & 7];
      float4 b0 = *(const float4*)(ur + off);
      float4 b1 = *(const float4*)(ur + off + 4);
      int4 p; p.x = pk_bf16(b0.x, b0.y); p.y = pk_bf16(b0.z, b0.w);
      p.z = pk_bf16(b1.x, b1.y); p.w = pk_bf16(b1.z, b1.w);
      accD = __builtin_amdgcn_mfma_f32_16x16x32_bf16(
          aV[ks], __builtin_bit_cast(bf16x8, p), accD, 0, 0, 0);
    }
    if (m < TI) {
      #pragma unroll
      for (int r = 0; r < 4; ++r) sD[wave][g * 4 + r][m] = accD[r];
    }
  }
  __syncthreads();

  float cb2v[4], cw3v[4], ab2v[2], aw3v[2];
  #pragma unroll
  for (int nt = 0; nt < 4; ++nt) { cb2v[nt] = cb2[nt * 16 + m]; cw3v[nt] = cW3[nt * 16 + m]; }
  #pragma unroll
  for (int nt = 0; nt < 2; ++nt) { ab2v[nt] = ab2[nt * 16 + m]; aw3v[nt] = aW3[nt * 16 + m]; }
  const float cb3s = cb3[0], ab3s = ab3[0];
  const bf16x8* bfr = (const bf16x8*)sFrag;
  const float inv128 = 0.0078125f;

  for (int it = 0; it < TI; ++it) {
    const int i = i0 + it;
    if (jt * 64 + wave * 16 + 15 <= i) continue;   // wave-uniform skip

    // ---- precomputed LN stats (f32 dot from sD) ----
    const float su = sSt[it * 2], qu = sSt[it * 2 + 1];
    const float dot = sD[wave][m][it];
    const float mean = (su + svj) * inv128;
    const float ex2  = __builtin_fmaf(2.f, dot, qu + qvj) * inv128;
    const float var  = ex2 - mean * mean;
    const float rstd = rsqrtf(var + 1e-5f);

    const float* su_row  = sU[it];
    const float* sua_row = sUa[it];

    // ---- cons phase 1: gelu(((U+V)-mean)*rstd*G + B), pack bf16 ----
    int4 pC[4];
    #pragma unroll
    for (int ks = 0; ks < 4; ++ks) {
      const int off = ks * 32 + g * 8;
      float4 u0 = *(const float4*)(su_row + off);
      float4 u1 = *(const float4*)(su_row + off + 4);
      float4 g0 = *(const float4*)(sG + off);
      float4 g1 = *(const float4*)(sG + off + 4);
      float4 b0 = *(const float4*)(sB + off);
      float4 b1 = *(const float4*)(sB + off + 4);
      float us[8] = {u0.x,u0.y,u0.z,u0.w,u1.x,u1.y,u1.z,u1.w};
      float gg[8] = {g0.x,g0.y,g0.z,g0.w,g1.x,g1.y,g1.z,g1.w};
      float bb[8] = {b0.x,b0.y,b0.z,b0.w,b1.x,b1.y,b1.z,b1.w};
      float y[8];
      #pragma unroll
      for (int s = 0; s < 8; ++s) {
        float x = us[s] + vC[ks][s];
        float tq = (x - mean) * rstd;
        y[s] = geluf(__builtin_fmaf(tq, gg[s], bb[s]));
      }
      pC[ks].x = pk_bf16(y[0], y[1]); pC[ks].y = pk_bf16(y[2], y[3]);
      pC[ks].z = pk_bf16(y[4], y[5]); pC[ks].w = pk_bf16(y[6], y[7]);
    }

    // ---- assoc phase 1: relu(Ua+Va), Va from global (L1-resident) ----
    int4 pA[4];
    #pragma unroll
    for (int ks = 0; ks < 4; ++ks) {
      const int off = ks * 32 + g * 8;
      float4 u0 = *(const float4*)(sua_row + off);
      float4 u1 = *(const float4*)(sua_row + off + 4);
      float4 v0 = *(const float4*)(Varow + off);
      float4 v1 = *(const float4*)(Varow + off + 4);
      float us[8] = {u0.x,u0.y,u0.z,u0.w,u1.x,u1.y,u1.z,u1.w};
      float vs[8] = {v0.x,v0.y,v0.z,v0.w,v1.x,v1.y,v1.z,v1.w};
      float r[8];
      #pragma unroll
      for (int s = 0; s < 8; ++s) r[s] = fmaxf(us[s] + vs[s], 0.f);
      pA[ks].x = pk_bf16(r[0], r[1]); pA[ks].y = pk_bf16(r[2], r[3]);
      pA[ks].z = pk_bf16(r[4], r[5]); pA[ks].w = pk_bf16(r[6], r[7]);
    }

    // ---- layer-2 GEMMs via MFMA ----
    f32x4 accC[4] = {zero, zero, zero, zero};
    f32x4 accA[2] = {zero, zero};
    #pragma unroll
    for (int ks = 0; ks < 4; ++ks) {
      bf16x8 aC = __builtin_bit_cast(bf16x8, pC[ks]);
      bf16x8 aA = __builtin_bit_cast(bf16x8, pA[ks]);
      #pragma unroll
      for (int nt = 0; nt < 4; ++nt)
        accC[nt] = __builtin_amdgcn_mfma_f32_16x16x32_bf16(
            aC, bfr[(nt * 4 + ks) * 64 + lane], accC[nt], 0, 0, 0);
      #pragma unroll
      for (int nt = 0; nt < 2; ++nt)
        accA[nt] = __builtin_amdgcn_mfma_f32_16x16x32_bf16(
            aA, bfr[1024 + (nt * 4 + ks) * 64 + lane], accA[nt], 0, 0, 0);
    }

    // ---- layer 3: bias + act + dot W3; DPP 16-lane reduction (VALU pipe) --
    float sc[4] = {0.f, 0.f, 0.f, 0.f};
    float sa[4] = {0.f, 0.f, 0.f, 0.f};
    #pragma unroll
    for (int nt = 0; nt < 4; ++nt)
      #pragma unroll
      for (int r = 0; r < 4; ++r)
        sc[r] = __builtin_fmaf(geluf(accC[nt][r] + cb2v[nt]), cw3v[nt], sc[r]);
    #pragma unroll
    for (int nt = 0; nt < 2; ++nt)
      #pragma unroll
      for (int r = 0; r < 4; ++r)
        sa[r] = __builtin_fmaf(fmaxf(accA[nt][r] + ab2v[nt], 0.f), aw3v[nt], sa[r]);
    #pragma unroll
    for (int r = 0; r < 4; ++r) { sc[r] = red16(sc[r]); sa[r] = red16(sa[r]); }

    if (m < 4) {
      const int jr = jt * 64 + wave * 16 + g * 4 + m;
      if (jr > i) {
        const int p = i * (2 * N_TR - i - 1) / 2 + (jr - i - 1);
        out[p]           = sigmoidf_(sc[m] + cb3s);
        out[P_PAIRS + p] = sigmoidf_(sa[m] + ab3s);
      }
    }
  }
}

extern "C" void kernel_launch(void* const* d_in, const int* in_sizes, int n_in,
                              void* d_out, int out_size, void* d_ws, size_t ws_size,
                              hipStream_t stream) {
  const float* emb = (const float*)d_in[0];
  const float* tf  = (const float*)d_in[1];
  const float* cW1 = (const float*)d_in[2];
  const float* cb1 = (const float*)d_in[3];
  const float* lng = (const float*)d_in[4];
  const float* lnb = (const float*)d_in[5];
  const float* cW2 = (const float*)d_in[6];
  const float* cb2 = (const float*)d_in[7];
  const float* cW3 = (const float*)d_in[8];
  const float* cb3 = (const float*)d_in[9];
  const float* aW1 = (const float*)d_in[10];
  const float* ab1 = (const float*)d_in[11];
  const float* aW2 = (const float*)d_in[12];
  const float* ab2 = (const float*)d_in[13];
  const float* aW3 = (const float*)d_in[14];
  const float* ab3 = (const float*)d_in[15];
  const float* iW1 = (const float*)d_in[16];
  const float* ib1 = (const float*)d_in[17];
  const float* iW2 = (const float*)d_in[18];
  const float* ib2 = (const float*)d_in[19];

  float* ws = (float*)d_ws;
  unsigned short* frag = (unsigned short*)((char*)d_ws + WS_FRAG_BYTES);
  float* out = (float*)d_out;

  hipLaunchKernelGGL(k_pre, dim3(816), dim3(256), 0, stream,
                     emb, tf, cW1, cb1, aW1, ab1, cW2, aW2,
                     iW1, ib1, iW2, ib2, ws, frag, out);
  hipLaunchKernelGGL(k_pairs, dim3(1088), dim3(256), 0, stream,
                     ws, frag, lng, lnb, cb2, cW3, cb3, ab2, aW3, ab3, out);
}